// Round 3
// baseline (4505.761 us; speedup 1.0000x reference)
//
#include <hip/hip_runtime.h>
#include <hip/hip_cooperative_groups.h>
#include <math.h>

namespace cg = cooperative_groups;

#define BB 8
#define TT 128
#define NN 512
#define HH 4
#define DD 2048      // N*HID
#define EE 16384
#define KTOT 4096    // 2048 (x) + 2048 (h)
#define NKB 128      // KTOT/32 kblocks

typedef __attribute__((ext_vector_type(8))) short short8;
typedef __attribute__((ext_vector_type(4))) float f32x4;

__device__ __forceinline__ float b2f(unsigned short u) {
    union { unsigned int i; float f; } v; v.i = ((unsigned int)u) << 16; return v.f;
}
__device__ __forceinline__ unsigned short f2b(float f) {
    union { float f; unsigned int i; } v; v.f = f;
    unsigned int r = v.i + 0x7fff + ((v.i >> 16) & 1);
    return (unsigned short)(r >> 16);
}

// ---------------- CSR build (edges identical every timestep) ----------------

__global__ void k_csr_zero(int* __restrict__ counts, int* __restrict__ fill) {
    int i = threadIdx.x;
    counts[i] = 0;
    fill[i] = 0;
}

__global__ void k_csr_count(const int* __restrict__ ei, int* __restrict__ counts) {
    int e = blockIdx.x * blockDim.x + threadIdx.x;
    if (e < EE) atomicAdd(&counts[ei[EE + e]], 1);
}

__global__ void k_csr_scan(const int* __restrict__ counts, int* __restrict__ offs) {
    int s = 0;
    for (int i = 0; i < NN; ++i) { offs[i] = s; s += counts[i]; }
    offs[NN] = s;
}

__global__ void k_csr_fill(const int* __restrict__ ei, const int* __restrict__ offs,
                           int* __restrict__ fill, int* __restrict__ csr_src) {
    int e = blockIdx.x * blockDim.x + threadIdx.x;
    if (e < EE) {
        int d = ei[EE + e];
        int pos = atomicAdd(&fill[d], 1);
        csr_src[offs[d] + pos] = ei[e];
    }
}

// ---------------- GAT (outputs bf16 seq[t][b][d]) ----------------

__global__ void k_gat0(const float* __restrict__ xseq, const float* __restrict__ W,
                       const float* __restrict__ as, const float* __restrict__ ad,
                       const float* __restrict__ bias, const int* __restrict__ offs,
                       const int* __restrict__ csr_src, unsigned short* __restrict__ seqout) {
    __shared__ float xr[NN];
    const int t = blockIdx.x;
    const int j = threadIdx.x;
    xr[j] = xseq[t * NN + j];
    __syncthreads();

    const float w0 = W[0], w1 = W[1], w2 = W[2], w3 = W[3];
    const float cs = w0 * as[0] + w1 * as[1] + w2 * as[2] + w3 * as[3];
    const float cd = w0 * ad[0] + w1 * ad[1] + w2 * ad[2] + w3 * ad[3];

    const float xj = xr[j];
    const float ed = cd * xj;
    float e0 = (cs + cd) * xj;
    e0 = e0 > 0.f ? e0 : 0.2f * e0;

    const int s0 = offs[j], s1 = offs[j + 1];
    float m = e0;
    for (int p = s0; p < s1; ++p) {
        float e = cs * xr[csr_src[p]] + ed;
        e = e > 0.f ? e : 0.2f * e;
        m = fmaxf(m, e);
    }
    float den = expf(e0 - m);
    float num = den * xj;
    for (int p = s0; p < s1; ++p) {
        int s = csr_src[p];
        float e = cs * xr[s] + ed;
        e = e > 0.f ? e : 0.2f * e;
        float wgt = expf(e - m);
        den += wgt;
        num += wgt * xr[s];
    }
    const float y = num / den;

    ushort4 o;
    o.x = f2b(fmaxf(w0 * y + bias[0], 0.f));
    o.y = f2b(fmaxf(w1 * y + bias[1], 0.f));
    o.z = f2b(fmaxf(w2 * y + bias[2], 0.f));
    o.w = f2b(fmaxf(w3 * y + bias[3], 0.f));
    *(ushort4*)(seqout + (size_t)t * BB * DD + (size_t)j * HH) = o;
}

__global__ void k_gat_rest(const float* __restrict__ xseq, const float* __restrict__ W,
                           const float* __restrict__ bias, unsigned short* __restrict__ seqout) {
    int n = blockIdx.x * blockDim.x + threadIdx.x;
    int t = n / (7 * NN);
    int rem = n - t * (7 * NN);
    int b = 1 + rem / NN;
    int j = rem - (b - 1) * NN;
    float x = xseq[((size_t)b * TT + t) * NN + j];
    const float w0 = W[0], w1 = W[1], w2 = W[2], w3 = W[3];
    ushort4 o;
    o.x = f2b(fmaxf(w0 * x + bias[0], 0.f));
    o.y = f2b(fmaxf(w1 * x + bias[1], 0.f));
    o.z = f2b(fmaxf(w2 * x + bias[2], 0.f));
    o.w = f2b(fmaxf(w3 * x + bias[3], 0.f));
    *(ushort4*)(seqout + (size_t)t * BB * DD + (size_t)b * DD + (size_t)j * HH) = o;
}

// ---------------- weight pack: f32 -> bf16 B-fragment tiles ----------------
// Frag (s,kb) position p (0..63) holds B[k=kb*32+(p>>4)*8+j][n=p&15], j=0..7.
// Lane mapping n=lane>>2, quad=lane&3: 4 consecutive lanes read 128 B of one
// row contiguously (coalesced f32 reads); write position = quad*16 + n.
__global__ __launch_bounds__(256) void k_pack_w(const float* __restrict__ wih,
                                                const float* __restrict__ whh,
                                                unsigned short* __restrict__ WP) {
    const int pair = blockIdx.x * 4 + (threadIdx.x >> 6);  // (s,kb): 0..65535
    const int lane = threadIdx.x & 63;
    const int s = pair >> 7, kb = pair & 127;
    const int n = lane >> 2, quad = lane & 3;
    const int d = (s >> 1) * 8 + (s & 1) * 4 + (n & 3);
    const int row = (n >> 2) * 2048 + d;
    const int k = kb * 32 + quad * 8;
    const float* src = (k < 2048) ? (wih + (size_t)row * 2048 + k)
                                  : (whh + (size_t)row * 2048 + (k - 2048));
    unsigned int u[4];
#pragma unroll
    for (int p = 0; p < 4; ++p)
        u[p] = (unsigned int)f2b(src[2 * p]) | ((unsigned int)f2b(src[2 * p + 1]) << 16);
    ((uint4*)WP)[(size_t)pair * 64 + quad * 16 + n] = make_uint4(u[0], u[1], u[2], u[3]);
}

// ---------------- misc ----------------

__global__ void k_init(float* __restrict__ p) {
    int i = blockIdx.x * blockDim.x + threadIdx.x;
    p[i] = 0.f;
}

// ---------------- persistent LSTM ----------------
// 256 blocks x 1024 thr (16 waves, 1 block/CU). Block b: d0=8b..8b+7, all gates
// = strips 2b(st=0: d0..d0+3), 2b+1(st=1: d0+4..d0+7). Wave (st=w>>3, ke=w&7)
// holds 16 weight B-frags in registers (64 VGPR) for kb=ke*16..+15, loaded ONCE.
// Then 128 timesteps in-kernel with grid.sync(); c lives in registers.
__global__ __launch_bounds__(1024, 4) void k_lstm_persist(
    const unsigned short* __restrict__ seq, const uint4* __restrict__ WPq,
    const float* __restrict__ b_ih, const float* __restrict__ b_hh,
    unsigned short* __restrict__ hb0, unsigned short* __restrict__ hb1) {
    __shared__ uint4 ldsA[NKB * 64];        // 128 KB A-fragments
    __shared__ float red[2][8][32][4];      // 8 KB k-partial D
    __shared__ float zbuf[4][8][8];         // [gate][d_local][batch]
    __shared__ float biasL[32];             // b_ih+b_hh for this block's 32 rows

    const int tid = threadIdx.x;
    const int wave = tid >> 6, lane = tid & 63;
    const int st = wave >> 3, ke = wave & 7;
    const int d0 = blockIdx.x * 8;
    const size_t sglob = (size_t)blockIdx.x * 2 + st;

    if (tid < 32) {
        const int g = tid >> 3, dl = tid & 7;
        const int row = g * 2048 + d0 + dl;
        biasL[tid] = b_ih[row] + b_hh[row];
    }

    // load this wave's 16 weight fragments into registers (coalesced, once)
    uint4 w[16];
    {
        const uint4* wp = WPq + (sglob * NKB + (size_t)ke * 16) * 64 + lane;
#pragma unroll
        for (int i = 0; i < 16; ++i) w[i] = wp[i * 64];
    }

    float creg = 0.f;   // c for tid<64: (batch=tid>>3, d=d0+(tid&7))
    cg::grid_group grid = cg::this_grid();

    for (int t = 0; t < TT; ++t) {
        const unsigned short* xt = seq + (size_t)t * BB * DD;
        const unsigned short* hin = (t & 1) ? hb1 : hb0;
        unsigned short* hout = (t & 1) ? hb0 : hb1;

        // stage x||h as A-frags: entry (kb,L): A[m=L&15 (dup of L&7)][k=kb*32+(L>>4)*8+j]
#pragma unroll
        for (int i = 0; i < 8; ++i) {
            const int idx = tid + 1024 * i;
            const int kb = idx >> 6, L = idx & 63;
            const int batch = L & 7;
            const int k = kb * 32 + ((L >> 4) << 3);
            const unsigned short* src = (k < 2048) ? (xt + batch * DD + k)
                                                   : (hin + batch * DD + (k - 2048));
            ldsA[idx] = *(const uint4*)src;
        }
        __syncthreads();

        f32x4 acc = {0.f, 0.f, 0.f, 0.f};
#pragma unroll
        for (int i = 0; i < 16; ++i) {
            uint4 au = ldsA[(ke * 16 + i) * 64 + lane];
            short8 a, b;
            __builtin_memcpy(&a, &au, 16);
            __builtin_memcpy(&b, &w[i], 16);
            acc = __builtin_amdgcn_mfma_f32_16x16x32_bf16(a, b, acc, 0, 0, 0);
        }
        if (lane < 32) *(f32x4*)&red[st][ke][lane][0] = acc;
        __syncthreads();

        // reduce 8 k-eighths -> zbuf (C layout: col=lane&15, row=(lane>>4)*4+reg)
        if (tid < 256) {
            const int st2 = tid >> 7, l2 = (tid & 127) >> 2, reg = tid & 3;
            float z = 0.f;
#pragma unroll
            for (int kk = 0; kk < 8; ++kk) z += red[st2][kk][l2][reg];
            const int batch = (l2 >> 4) * 4 + reg;
            const int n = l2 & 15;
            zbuf[n >> 2][st2 * 4 + (n & 3)][batch] = z;
        }
        __syncthreads();

        if (tid < 64) {
            const int dl = tid & 7, batch = tid >> 3;
            const float zi = zbuf[0][dl][batch] + biasL[dl];
            const float zf = zbuf[1][dl][batch] + biasL[8 + dl];
            const float zg = zbuf[2][dl][batch] + biasL[16 + dl];
            const float zo = zbuf[3][dl][batch] + biasL[24 + dl];
            const float si = 1.f / (1.f + expf(-zi));
            const float sf = 1.f / (1.f + expf(-zf));
            const float so = 1.f / (1.f + expf(-zo));
            const float tg = tanhf(zg);
            creg = sf * creg + si * tg;
            hout[batch * DD + d0 + dl] = f2b(so * tanhf(creg));
        }
        grid.sync();
    }
}

// ---------------- final linear: out[b,o] = h[b,:]·w_lin[o,:] + b_lin[o] ----------------
__global__ void k_final(const unsigned short* __restrict__ h, const float* __restrict__ w_lin,
                        const float* __restrict__ b_lin, float* __restrict__ out) {
    const int wave = threadIdx.x >> 6;
    const int lane = threadIdx.x & 63;
    const int o = blockIdx.x * 4 + wave;
    const float4* w4 = (const float4*)(w_lin + (size_t)o * DD);

    float acc[8];
#pragma unroll
    for (int b = 0; b < 8; ++b) acc[b] = 0.f;
#pragma unroll 2
    for (int it = 0; it < 8; ++it) {
        const int k4 = it * 64 + lane;
        float4 wv = w4[k4];
#pragma unroll
        for (int b = 0; b < 8; ++b) {
            ushort4 hv = *(const ushort4*)(h + (size_t)b * DD + 4 * (size_t)k4);
            acc[b] += wv.x * b2f(hv.x) + wv.y * b2f(hv.y) +
                      wv.z * b2f(hv.z) + wv.w * b2f(hv.w);
        }
    }
#pragma unroll
    for (int b = 0; b < 8; ++b) {
        float v = acc[b];
        v += __shfl_xor(v, 32, 64);
        v += __shfl_xor(v, 16, 64);
        v += __shfl_xor(v, 8, 64);
        v += __shfl_xor(v, 4, 64);
        v += __shfl_xor(v, 2, 64);
        v += __shfl_xor(v, 1, 64);
        acc[b] = v;
    }
    if (lane < 8) out[(size_t)lane * NN + o] = acc[lane] + b_lin[o];
}

// ---------------- launch ----------------

extern "C" void kernel_launch(void* const* d_in, const int* in_sizes, int n_in,
                              void* d_out, int out_size, void* d_ws, size_t ws_size,
                              hipStream_t stream) {
    const float* xseq  = (const float*)d_in[0];
    const float* gat_w = (const float*)d_in[1];
    const float* a_src = (const float*)d_in[2];
    const float* a_dst = (const float*)d_in[3];
    const float* g_b   = (const float*)d_in[4];
    const float* w_ih  = (const float*)d_in[5];
    const float* w_hh  = (const float*)d_in[6];
    const float* b_ih  = (const float*)d_in[7];
    const float* b_hh  = (const float*)d_in[8];
    const float* w_lin = (const float*)d_in[9];
    const float* b_lin = (const float*)d_in[10];
    const int*   eidx  = (const int*)d_in[11];
    float* out = (float*)d_out;

    // workspace layout
    unsigned short* seq = (unsigned short*)d_ws;                 // T*B*D bf16 (4 MB)
    unsigned short* WP  = seq + (size_t)TT * BB * DD;            // 8192*4096 bf16 (64 MB)
    unsigned short* hb0 = WP + (size_t)8192 * KTOT;              // B*D bf16 (32 KB)
    unsigned short* hb1 = hb0 + BB * DD;                         // B*D bf16 (32 KB)
    int* counts  = (int*)(hb1 + BB * DD);
    int* offs    = counts + NN;
    int* fill    = offs + NN + 1;
    int* csr_src = fill + NN;

    // CSR build
    k_csr_zero<<<1, NN, 0, stream>>>(counts, fill);
    k_csr_count<<<EE / 256, 256, 0, stream>>>(eidx, counts);
    k_csr_scan<<<1, 1, 0, stream>>>(counts, offs);
    k_csr_fill<<<EE / 256, 256, 0, stream>>>(eidx, offs, fill, csr_src);

    // weight pack (bf16, B-frag swizzled)
    k_pack_w<<<16384, 256, 0, stream>>>(w_ih, w_hh, WP);

    // GAT -> seq (bf16)
    k_gat0<<<TT, NN, 0, stream>>>(xseq, gat_w, a_src, a_dst, g_b, offs, csr_src, seq);
    k_gat_rest<<<(TT * 7 * NN) / 256, 256, 0, stream>>>(xseq, gat_w, g_b, seq);

    // zero hb0 + hb1 (64 KB = 16384 floats)
    k_init<<<64, 256, 0, stream>>>((float*)hb0);

    // persistent cooperative LSTM: all 128 steps in one kernel
    {
        void* kargs[] = {
            (void*)&seq, (void*)&WP, (void*)&b_ih, (void*)&b_hh,
            (void*)&hb0, (void*)&hb1,
        };
        hipLaunchCooperativeKernel((const void*)k_lstm_persist, dim3(256), dim3(1024),
                                   kargs, 0, stream);
    }

    // final h is in hb0 after 128 steps
    k_final<<<NN / 4, 256, 0, stream>>>(hb0, w_lin, b_lin, out);
}

// Round 4
// 1619.168 us; speedup vs baseline: 2.7828x; 2.7828x over previous
//
#include <hip/hip_runtime.h>
#include <hip/hip_cooperative_groups.h>
#include <math.h>

#define BB 8
#define TT 128
#define NN 512
#define HH 4
#define DD 2048      // N*HID
#define EE 16384
#define KTOT 4096    // 2048 (x) + 2048 (h)
#define NKB 128      // KTOT/32 kblocks
#define XROW 4112    // 4096 + 16 pad shorts (32 B) per batch row in LDS

typedef __attribute__((ext_vector_type(8))) short short8;
typedef __attribute__((ext_vector_type(4))) float f32x4;

__device__ __forceinline__ float b2f(unsigned short u) {
    union { unsigned int i; float f; } v; v.i = ((unsigned int)u) << 16; return v.f;
}
__device__ __forceinline__ unsigned short f2b(float f) {
    union { float f; unsigned int i; } v; v.f = f;
    unsigned int r = v.i + 0x7fff + ((v.i >> 16) & 1);
    return (unsigned short)(r >> 16);
}

// ---------------- CSR build (edges identical every timestep) ----------------

__global__ void k_csr_zero(int* __restrict__ counts, int* __restrict__ fill) {
    int i = threadIdx.x;
    counts[i] = 0;
    fill[i] = 0;
}

__global__ void k_csr_count(const int* __restrict__ ei, int* __restrict__ counts) {
    int e = blockIdx.x * blockDim.x + threadIdx.x;
    if (e < EE) atomicAdd(&counts[ei[EE + e]], 1);
}

__global__ void k_csr_scan(const int* __restrict__ counts, int* __restrict__ offs) {
    int s = 0;
    for (int i = 0; i < NN; ++i) { offs[i] = s; s += counts[i]; }
    offs[NN] = s;
}

__global__ void k_csr_fill(const int* __restrict__ ei, const int* __restrict__ offs,
                           int* __restrict__ fill, int* __restrict__ csr_src) {
    int e = blockIdx.x * blockDim.x + threadIdx.x;
    if (e < EE) {
        int d = ei[EE + e];
        int pos = atomicAdd(&fill[d], 1);
        csr_src[offs[d] + pos] = ei[e];
    }
}

// ---------------- GAT (outputs bf16 seq[t][b][d]) ----------------

__global__ void k_gat0(const float* __restrict__ xseq, const float* __restrict__ W,
                       const float* __restrict__ as, const float* __restrict__ ad,
                       const float* __restrict__ bias, const int* __restrict__ offs,
                       const int* __restrict__ csr_src, unsigned short* __restrict__ seqout) {
    __shared__ float xr[NN];
    const int t = blockIdx.x;
    const int j = threadIdx.x;
    xr[j] = xseq[t * NN + j];
    __syncthreads();

    const float w0 = W[0], w1 = W[1], w2 = W[2], w3 = W[3];
    const float cs = w0 * as[0] + w1 * as[1] + w2 * as[2] + w3 * as[3];
    const float cd = w0 * ad[0] + w1 * ad[1] + w2 * ad[2] + w3 * ad[3];

    const float xj = xr[j];
    const float ed = cd * xj;
    float e0 = (cs + cd) * xj;
    e0 = e0 > 0.f ? e0 : 0.2f * e0;

    const int s0 = offs[j], s1 = offs[j + 1];
    float m = e0;
    for (int p = s0; p < s1; ++p) {
        float e = cs * xr[csr_src[p]] + ed;
        e = e > 0.f ? e : 0.2f * e;
        m = fmaxf(m, e);
    }
    float den = expf(e0 - m);
    float num = den * xj;
    for (int p = s0; p < s1; ++p) {
        int s = csr_src[p];
        float e = cs * xr[s] + ed;
        e = e > 0.f ? e : 0.2f * e;
        float wgt = expf(e - m);
        den += wgt;
        num += wgt * xr[s];
    }
    const float y = num / den;

    ushort4 o;
    o.x = f2b(fmaxf(w0 * y + bias[0], 0.f));
    o.y = f2b(fmaxf(w1 * y + bias[1], 0.f));
    o.z = f2b(fmaxf(w2 * y + bias[2], 0.f));
    o.w = f2b(fmaxf(w3 * y + bias[3], 0.f));
    *(ushort4*)(seqout + (size_t)t * BB * DD + (size_t)j * HH) = o;
}

__global__ void k_gat_rest(const float* __restrict__ xseq, const float* __restrict__ W,
                           const float* __restrict__ bias, unsigned short* __restrict__ seqout) {
    int n = blockIdx.x * blockDim.x + threadIdx.x;
    int t = n / (7 * NN);
    int rem = n - t * (7 * NN);
    int b = 1 + rem / NN;
    int j = rem - (b - 1) * NN;
    float x = xseq[((size_t)b * TT + t) * NN + j];
    const float w0 = W[0], w1 = W[1], w2 = W[2], w3 = W[3];
    ushort4 o;
    o.x = f2b(fmaxf(w0 * x + bias[0], 0.f));
    o.y = f2b(fmaxf(w1 * x + bias[1], 0.f));
    o.z = f2b(fmaxf(w2 * x + bias[2], 0.f));
    o.w = f2b(fmaxf(w3 * x + bias[3], 0.f));
    *(ushort4*)(seqout + (size_t)t * BB * DD + (size_t)b * DD + (size_t)j * HH) = o;
}

// ---------------- weight pack: f32 -> bf16 B-fragment tiles ----------------
__global__ __launch_bounds__(256) void k_pack_w(const float* __restrict__ wih,
                                                const float* __restrict__ whh,
                                                unsigned short* __restrict__ WP) {
    const int pair = blockIdx.x * 4 + (threadIdx.x >> 6);  // (s,kb): 0..65535
    const int lane = threadIdx.x & 63;
    const int s = pair >> 7, kb = pair & 127;
    const int n = lane >> 2, quad = lane & 3;
    const int d = (s >> 1) * 8 + (s & 1) * 4 + (n & 3);
    const int row = (n >> 2) * 2048 + d;
    const int k = kb * 32 + quad * 8;
    const float* src = (k < 2048) ? (wih + (size_t)row * 2048 + k)
                                  : (whh + (size_t)row * 2048 + (k - 2048));
    unsigned int u[4];
#pragma unroll
    for (int p = 0; p < 4; ++p)
        u[p] = (unsigned int)f2b(src[2 * p]) | ((unsigned int)f2b(src[2 * p + 1]) << 16);
    ((uint4*)WP)[(size_t)pair * 64 + quad * 16 + n] = make_uint4(u[0], u[1], u[2], u[3]);
}

// ---------------- zero h buffers + barrier state ----------------

__global__ void k_zero(unsigned int* __restrict__ hb, unsigned int* __restrict__ bar) {
    int i = blockIdx.x * blockDim.x + threadIdx.x;
    if (i < 16384) hb[i] = 0u;     // hb0 + hb1 (64 KB)
    if (i < 384) bar[i] = 0u;      // flags[256] + go + padding
}

// ---------------- hand-rolled grid barrier (agent-scope flags in L3) ----------------

__device__ __forceinline__ void gbar(unsigned int* flags, unsigned int* go, unsigned int gen) {
    __syncthreads();   // all block work done; h stores drained (vmcnt 0)
    const int tid = threadIdx.x;
    if (blockIdx.x == 0) {
        if (tid >= 1 && tid < 256) {
            while (__hip_atomic_load(&flags[tid], __ATOMIC_RELAXED,
                                     __HIP_MEMORY_SCOPE_AGENT) < gen) {}
        }
        __syncthreads();           // all 255 arrivals observed
        if (tid == 0) {
            __hip_atomic_store(go, gen, __ATOMIC_RELEASE, __HIP_MEMORY_SCOPE_AGENT);
            __threadfence();       // acquire: invalidate stale L1/L2 before reading h
        }
        __syncthreads();
    } else {
        if (tid == 0) {
            __hip_atomic_store(&flags[blockIdx.x], gen, __ATOMIC_RELEASE,
                               __HIP_MEMORY_SCOPE_AGENT);
            while (__hip_atomic_load(go, __ATOMIC_RELAXED,
                                     __HIP_MEMORY_SCOPE_AGENT) < gen) {
                __builtin_amdgcn_s_sleep(1);
            }
            __threadfence();       // acquire
        }
        __syncthreads();
    }
}

// ---------------- persistent LSTM ----------------
// 256 blocks x 1024 thr (cooperative: residency guaranteed). Block b: d0=8b..8b+7,
// strips 2b (st=0) and 2b+1 (st=1). Wave (st=w>>3, ke=w&7) holds 16 weight B-frags
// in registers, loaded ONCE. 128 timesteps in-kernel; hand-rolled grid barrier.
__global__ __launch_bounds__(1024, 4) void k_lstm_persist(
    const unsigned short* __restrict__ seq, const uint4* __restrict__ WPq,
    const float* __restrict__ b_ih, const float* __restrict__ b_hh,
    unsigned short* __restrict__ hb0, unsigned short* __restrict__ hb1,
    unsigned int* __restrict__ flags, unsigned int* __restrict__ go) {
    __shared__ unsigned short xh[8][XROW];  // 65792 B unique x||h image, padded rows
    __shared__ float red[2][8][32][4];      // 8 KB k-partial D
    __shared__ float zbuf[4][8][8];         // [gate][d_local][batch]
    __shared__ float biasL[32];

    const int tid = threadIdx.x;
    const int wave = tid >> 6, lane = tid & 63;
    const int st = wave >> 3, ke = wave & 7;
    const int d0 = blockIdx.x * 8;
    const size_t sglob = (size_t)blockIdx.x * 2 + st;

    if (tid < 32) {
        const int g = tid >> 3, dl = tid & 7;
        const int row = g * 2048 + d0 + dl;
        biasL[tid] = b_ih[row] + b_hh[row];
    }

    // load this wave's 16 weight fragments into registers (once)
    uint4 w[16];
    {
        const uint4* wp = WPq + (sglob * NKB + (size_t)ke * 16) * 64 + lane;
#pragma unroll
        for (int i = 0; i < 16; ++i) w[i] = wp[i * 64];
    }

    // A-operand LDS read base for this lane: batch = lane&7, quad = lane>>4
    const unsigned short* arow = &xh[lane & 7][(lane >> 4) << 3];

    float creg = 0.f;   // c for tid<64: (batch=tid>>3, d=d0+(tid&7))

    for (int t = 0; t < TT; ++t) {
        const unsigned short* xt = seq + (size_t)t * BB * DD;
        const unsigned short* hin = (t & 1) ? hb1 : hb0;
        unsigned short* hout = (t & 1) ? hb0 : hb1;

        // stage unique x||h image: chunk c (16 B): batch=c>>9, k=(c&511)*8
#pragma unroll
        for (int i = 0; i < 4; ++i) {
            const int c = tid + 1024 * i;
            const int batch = c >> 9;
            const int k = (c & 511) << 3;
            const unsigned short* src = (k < 2048) ? (xt + batch * DD + k)
                                                   : (hin + batch * DD + (k - 2048));
            *(uint4*)&xh[batch][k] = *(const uint4*)src;
        }
        __syncthreads();

        f32x4 acc = {0.f, 0.f, 0.f, 0.f};
#pragma unroll
        for (int i = 0; i < 16; ++i) {
            const int kb = ke * 16 + i;
            short8 a = *(const short8*)(arow + (kb << 5));
            short8 b;
            __builtin_memcpy(&b, &w[i], 16);
            acc = __builtin_amdgcn_mfma_f32_16x16x32_bf16(a, b, acc, 0, 0, 0);
        }
        if (lane < 32) *(f32x4*)&red[st][ke][lane][0] = acc;
        __syncthreads();

        // reduce 8 k-eighths -> zbuf (C layout: col=lane&15, row=(lane>>4)*4+reg)
        if (tid < 256) {
            const int st2 = tid >> 7, l2 = (tid & 127) >> 2, reg = tid & 3;
            float z = 0.f;
#pragma unroll
            for (int kk = 0; kk < 8; ++kk) z += red[st2][kk][l2][reg];
            const int batch = (l2 >> 4) * 4 + reg;
            const int n = l2 & 15;
            zbuf[n >> 2][st2 * 4 + (n & 3)][batch] = z;
        }
        __syncthreads();

        if (tid < 64) {
            const int dl = tid & 7, batch = tid >> 3;
            const float zi = zbuf[0][dl][batch] + biasL[dl];
            const float zf = zbuf[1][dl][batch] + biasL[8 + dl];
            const float zg = zbuf[2][dl][batch] + biasL[16 + dl];
            const float zo = zbuf[3][dl][batch] + biasL[24 + dl];
            const float si = 1.f / (1.f + expf(-zi));
            const float sf = 1.f / (1.f + expf(-zf));
            const float so = 1.f / (1.f + expf(-zo));
            const float tg = tanhf(zg);
            creg = sf * creg + si * tg;
            hout[batch * DD + d0 + dl] = f2b(so * tanhf(creg));
        }
        if (t != TT - 1) gbar(flags, go, (unsigned int)(t + 1));
    }
}

// ---------------- final linear: out[b,o] = h[b,:]·w_lin[o,:] + b_lin[o] ----------------
__global__ void k_final(const unsigned short* __restrict__ h, const float* __restrict__ w_lin,
                        const float* __restrict__ b_lin, float* __restrict__ out) {
    const int wave = threadIdx.x >> 6;
    const int lane = threadIdx.x & 63;
    const int o = blockIdx.x * 4 + wave;
    const float4* w4 = (const float4*)(w_lin + (size_t)o * DD);

    float acc[8];
#pragma unroll
    for (int b = 0; b < 8; ++b) acc[b] = 0.f;
#pragma unroll 2
    for (int it = 0; it < 8; ++it) {
        const int k4 = it * 64 + lane;
        float4 wv = w4[k4];
#pragma unroll
        for (int b = 0; b < 8; ++b) {
            ushort4 hv = *(const ushort4*)(h + (size_t)b * DD + 4 * (size_t)k4);
            acc[b] += wv.x * b2f(hv.x) + wv.y * b2f(hv.y) +
                      wv.z * b2f(hv.z) + wv.w * b2f(hv.w);
        }
    }
#pragma unroll
    for (int b = 0; b < 8; ++b) {
        float v = acc[b];
        v += __shfl_xor(v, 32, 64);
        v += __shfl_xor(v, 16, 64);
        v += __shfl_xor(v, 8, 64);
        v += __shfl_xor(v, 4, 64);
        v += __shfl_xor(v, 2, 64);
        v += __shfl_xor(v, 1, 64);
        acc[b] = v;
    }
    if (lane < 8) out[(size_t)lane * NN + o] = acc[lane] + b_lin[o];
}

// ---------------- launch ----------------

extern "C" void kernel_launch(void* const* d_in, const int* in_sizes, int n_in,
                              void* d_out, int out_size, void* d_ws, size_t ws_size,
                              hipStream_t stream) {
    const float* xseq  = (const float*)d_in[0];
    const float* gat_w = (const float*)d_in[1];
    const float* a_src = (const float*)d_in[2];
    const float* a_dst = (const float*)d_in[3];
    const float* g_b   = (const float*)d_in[4];
    const float* w_ih  = (const float*)d_in[5];
    const float* w_hh  = (const float*)d_in[6];
    const float* b_ih  = (const float*)d_in[7];
    const float* b_hh  = (const float*)d_in[8];
    const float* w_lin = (const float*)d_in[9];
    const float* b_lin = (const float*)d_in[10];
    const int*   eidx  = (const int*)d_in[11];
    float* out = (float*)d_out;

    // workspace layout
    unsigned short* seq = (unsigned short*)d_ws;                 // T*B*D bf16 (4 MB)
    unsigned short* WP  = seq + (size_t)TT * BB * DD;            // 64 MB packed weights
    unsigned short* hb0 = WP + (size_t)8192 * KTOT;              // B*D bf16
    unsigned short* hb1 = hb0 + BB * DD;                         // B*D bf16
    unsigned int* bar   = (unsigned int*)(hb1 + BB * DD);        // flags[256], go @320
    unsigned int* flags = bar;
    unsigned int* go    = bar + 320;
    int* counts  = (int*)(bar + 384);
    int* offs    = counts + NN;
    int* fill    = offs + NN + 1;
    int* csr_src = fill + NN;

    // CSR build
    k_csr_zero<<<1, NN, 0, stream>>>(counts, fill);
    k_csr_count<<<EE / 256, 256, 0, stream>>>(eidx, counts);
    k_csr_scan<<<1, 1, 0, stream>>>(counts, offs);
    k_csr_fill<<<EE / 256, 256, 0, stream>>>(eidx, offs, fill, csr_src);

    // weight pack (bf16, B-frag swizzled)
    k_pack_w<<<16384, 256, 0, stream>>>(w_ih, w_hh, WP);

    // GAT -> seq (bf16)
    k_gat0<<<TT, NN, 0, stream>>>(xseq, gat_w, a_src, a_dst, g_b, offs, csr_src, seq);
    k_gat_rest<<<(TT * 7 * NN) / 256, 256, 0, stream>>>(xseq, gat_w, g_b, seq);

    // zero h buffers + barrier state (poisoned with 0xAA each timed call!)
    k_zero<<<64, 256, 0, stream>>>((unsigned int*)hb0, bar);

    // persistent cooperative LSTM with hand-rolled grid barrier
    {
        void* kargs[] = {
            (void*)&seq, (void*)&WP, (void*)&b_ih, (void*)&b_hh,
            (void*)&hb0, (void*)&hb1, (void*)&flags, (void*)&go,
        };
        hipLaunchCooperativeKernel((const void*)k_lstm_persist, dim3(256), dim3(1024),
                                   kargs, 0, stream);
    }

    // final h is in hb0 after 128 steps
    k_final<<<NN / 4, 256, 0, stream>>>(hb0, w_lin, b_lin, out);
}

// Round 5
// 964.517 us; speedup vs baseline: 4.6715x; 1.6787x over previous
//
#include <hip/hip_runtime.h>
#include <hip/hip_cooperative_groups.h>
#include <math.h>

#define BB 8
#define TT 128
#define NN 512
#define HH 4
#define DD 2048      // N*HID
#define EE 16384
#define KTOT 4096    // 2048 (x) + 2048 (h)
#define NKB 128      // KTOT/32 kblocks
#define XROW 4112    // 4096 + 16 pad shorts (32 B) per batch row in LDS
#define FPAD 16      // flag padding (dwords) -> one flag per 64 B

typedef __attribute__((ext_vector_type(8))) short short8;
typedef __attribute__((ext_vector_type(4))) float f32x4;

__device__ __forceinline__ float b2f(unsigned short u) {
    union { unsigned int i; float f; } v; v.i = ((unsigned int)u) << 16; return v.f;
}
__device__ __forceinline__ unsigned short f2b(float f) {
    union { float f; unsigned int i; } v; v.f = f;
    unsigned int r = v.i + 0x7fff + ((v.i >> 16) & 1);
    return (unsigned short)(r >> 16);
}

// ---------------- CSR build (edges identical every timestep) ----------------

__global__ void k_csr_zero(int* __restrict__ counts, int* __restrict__ fill) {
    int i = threadIdx.x;
    counts[i] = 0;
    fill[i] = 0;
}

__global__ void k_csr_count(const int* __restrict__ ei, int* __restrict__ counts) {
    int e = blockIdx.x * blockDim.x + threadIdx.x;
    if (e < EE) atomicAdd(&counts[ei[EE + e]], 1);
}

__global__ void k_csr_scan(const int* __restrict__ counts, int* __restrict__ offs) {
    int s = 0;
    for (int i = 0; i < NN; ++i) { offs[i] = s; s += counts[i]; }
    offs[NN] = s;
}

__global__ void k_csr_fill(const int* __restrict__ ei, const int* __restrict__ offs,
                           int* __restrict__ fill, int* __restrict__ csr_src) {
    int e = blockIdx.x * blockDim.x + threadIdx.x;
    if (e < EE) {
        int d = ei[EE + e];
        int pos = atomicAdd(&fill[d], 1);
        csr_src[offs[d] + pos] = ei[e];
    }
}

// ---------------- GAT (outputs bf16 seq[t][b][d]) ----------------

__global__ void k_gat0(const float* __restrict__ xseq, const float* __restrict__ W,
                       const float* __restrict__ as, const float* __restrict__ ad,
                       const float* __restrict__ bias, const int* __restrict__ offs,
                       const int* __restrict__ csr_src, unsigned short* __restrict__ seqout) {
    __shared__ float xr[NN];
    const int t = blockIdx.x;
    const int j = threadIdx.x;
    xr[j] = xseq[t * NN + j];
    __syncthreads();

    const float w0 = W[0], w1 = W[1], w2 = W[2], w3 = W[3];
    const float cs = w0 * as[0] + w1 * as[1] + w2 * as[2] + w3 * as[3];
    const float cd = w0 * ad[0] + w1 * ad[1] + w2 * ad[2] + w3 * ad[3];

    const float xj = xr[j];
    const float ed = cd * xj;
    float e0 = (cs + cd) * xj;
    e0 = e0 > 0.f ? e0 : 0.2f * e0;

    const int s0 = offs[j], s1 = offs[j + 1];
    float m = e0;
    for (int p = s0; p < s1; ++p) {
        float e = cs * xr[csr_src[p]] + ed;
        e = e > 0.f ? e : 0.2f * e;
        m = fmaxf(m, e);
    }
    float den = expf(e0 - m);
    float num = den * xj;
    for (int p = s0; p < s1; ++p) {
        int s = csr_src[p];
        float e = cs * xr[s] + ed;
        e = e > 0.f ? e : 0.2f * e;
        float wgt = expf(e - m);
        den += wgt;
        num += wgt * xr[s];
    }
    const float y = num / den;

    ushort4 o;
    o.x = f2b(fmaxf(w0 * y + bias[0], 0.f));
    o.y = f2b(fmaxf(w1 * y + bias[1], 0.f));
    o.z = f2b(fmaxf(w2 * y + bias[2], 0.f));
    o.w = f2b(fmaxf(w3 * y + bias[3], 0.f));
    *(ushort4*)(seqout + (size_t)t * BB * DD + (size_t)j * HH) = o;
}

__global__ void k_gat_rest(const float* __restrict__ xseq, const float* __restrict__ W,
                           const float* __restrict__ bias, unsigned short* __restrict__ seqout) {
    int n = blockIdx.x * blockDim.x + threadIdx.x;
    int t = n / (7 * NN);
    int rem = n - t * (7 * NN);
    int b = 1 + rem / NN;
    int j = rem - (b - 1) * NN;
    float x = xseq[((size_t)b * TT + t) * NN + j];
    const float w0 = W[0], w1 = W[1], w2 = W[2], w3 = W[3];
    ushort4 o;
    o.x = f2b(fmaxf(w0 * x + bias[0], 0.f));
    o.y = f2b(fmaxf(w1 * x + bias[1], 0.f));
    o.z = f2b(fmaxf(w2 * x + bias[2], 0.f));
    o.w = f2b(fmaxf(w3 * x + bias[3], 0.f));
    *(ushort4*)(seqout + (size_t)t * BB * DD + (size_t)b * DD + (size_t)j * HH) = o;
}

// ---------------- weight pack: f32 -> bf16 B-fragment tiles ----------------
__global__ __launch_bounds__(256) void k_pack_w(const float* __restrict__ wih,
                                                const float* __restrict__ whh,
                                                unsigned short* __restrict__ WP) {
    const int pair = blockIdx.x * 4 + (threadIdx.x >> 6);  // (s,kb): 0..65535
    const int lane = threadIdx.x & 63;
    const int s = pair >> 7, kb = pair & 127;
    const int n = lane >> 2, quad = lane & 3;
    const int d = (s >> 1) * 8 + (s & 1) * 4 + (n & 3);
    const int row = (n >> 2) * 2048 + d;
    const int k = kb * 32 + quad * 8;
    const float* src = (k < 2048) ? (wih + (size_t)row * 2048 + k)
                                  : (whh + (size_t)row * 2048 + (k - 2048));
    unsigned int u[4];
#pragma unroll
    for (int p = 0; p < 4; ++p)
        u[p] = (unsigned int)f2b(src[2 * p]) | ((unsigned int)f2b(src[2 * p + 1]) << 16);
    ((uint4*)WP)[(size_t)pair * 64 + quad * 16 + n] = make_uint4(u[0], u[1], u[2], u[3]);
}

// ---------------- zero h buffers + barrier flags ----------------

__global__ void k_zero(unsigned int* __restrict__ hb, unsigned int* __restrict__ bar) {
    int i = blockIdx.x * blockDim.x + threadIdx.x;
    if (i < 16384) hb[i] = 0u;     // hb0 + hb1 (64 KB)
    if (i < 256 * FPAD) bar[i] = 0u;
}

// ---------------- persistent LSTM ----------------
// 256 blocks x 1024 thr (cooperative: residency guaranteed). Block b: d0=8b..8b+7,
// strips 2b (st=0) and 2b+1 (st=1). Wave (st=w>>3, ke=w&7) holds 16 weight B-frags
// in registers, loaded ONCE. 128 timesteps in-kernel. All cross-block traffic
// (h, flags) is agent-scope sc1 -> no L2 writeback/invalidate ever needed.
__global__ __launch_bounds__(1024, 4) void k_lstm_persist(
    const unsigned short* __restrict__ seq, const uint4* __restrict__ WPq,
    const float* __restrict__ b_ih, const float* __restrict__ b_hh,
    unsigned short* __restrict__ hb0, unsigned short* __restrict__ hb1,
    unsigned int* __restrict__ flags) {
    __shared__ unsigned short xh[8][XROW];  // 65792 B unique x||h image, padded rows
    __shared__ float red[2][8][32][4];      // 8 KB k-partial D
    __shared__ float zbuf[4][8][8];         // [gate][d_local][batch]
    __shared__ float biasL[32];

    const int tid = threadIdx.x;
    const int wave = tid >> 6, lane = tid & 63;
    const int st = wave >> 3, ke = wave & 7;
    const int d0 = blockIdx.x * 8;
    const size_t sglob = (size_t)blockIdx.x * 2 + st;

    if (tid < 32) {
        const int g = tid >> 3, dl = tid & 7;
        const int row = g * 2048 + d0 + dl;
        biasL[tid] = b_ih[row] + b_hh[row];
    }

    // load this wave's 16 weight fragments into registers (once)
    uint4 w[16];
    {
        const uint4* wp = WPq + (sglob * NKB + (size_t)ke * 16) * 64 + lane;
#pragma unroll
        for (int i = 0; i < 16; ++i) w[i] = wp[i * 64];
    }

    // A-operand LDS read base for this lane: batch = lane&7, quad = lane>>4
    const unsigned short* arow = &xh[lane & 7][(lane >> 4) << 3];

    float creg0 = 0.f, creg1 = 0.f;   // c for tid<32: (batch=tid>>2, d=d0+(tid&3)*2 {+1})

    for (int t = 0; t < TT; ++t) {
        const unsigned short* xt = seq + (size_t)t * BB * DD;
        const unsigned short* hin = (t & 1) ? hb1 : hb0;
        unsigned short* hout = (t & 1) ? hb0 : hb1;

        // stage x part (k<2048) with regular uint4 loads — overlaps barrier wait
#pragma unroll
        for (int i = 0; i < 2; ++i) {
            const int c = tid + 1024 * i;            // 2048 chunks of 16 B
            const int batch = c >> 8;
            const int k = (c & 255) << 3;
            *(uint4*)&xh[batch][k] = *(const uint4*)(xt + batch * DD + k);
        }

        // one-hop barrier: wait for all 256 flag stores of step t-1
        if (t > 0 && tid < 256) {
            const unsigned int gen = (unsigned int)t;
            while (__hip_atomic_load(&flags[tid * FPAD], __ATOMIC_RELAXED,
                                     __HIP_MEMORY_SCOPE_AGENT) < gen) {}
        }
        __syncthreads();

        // stage h part (k>=2048) with sc1 dword loads (bypass stale L2)
        const unsigned int* hw = (const unsigned int*)hin;
#pragma unroll
        for (int i = 0; i < 8; ++i) {
            const int widx = tid + 1024 * i;         // 8192 dwords
            const int batch = widx >> 10;
            const int dw = widx & 1023;
            unsigned int v = __hip_atomic_load(&hw[widx], __ATOMIC_RELAXED,
                                               __HIP_MEMORY_SCOPE_AGENT);
            ((unsigned int*)&xh[batch][2048])[dw] = v;
        }
        __syncthreads();

        f32x4 acc = {0.f, 0.f, 0.f, 0.f};
#pragma unroll
        for (int i = 0; i < 16; ++i) {
            const int kb = ke * 16 + i;
            short8 a = *(const short8*)(arow + (kb << 5));
            short8 b;
            __builtin_memcpy(&b, &w[i], 16);
            acc = __builtin_amdgcn_mfma_f32_16x16x32_bf16(a, b, acc, 0, 0, 0);
        }
        if (lane < 32) *(f32x4*)&red[st][ke][lane][0] = acc;
        __syncthreads();

        // reduce 8 k-eighths -> zbuf (C layout: col=lane&15, row=(lane>>4)*4+reg)
        if (tid < 256) {
            const int st2 = tid >> 7, l2 = (tid & 127) >> 2, reg = tid & 3;
            float z = 0.f;
#pragma unroll
            for (int kk = 0; kk < 8; ++kk) z += red[st2][kk][l2][reg];
            const int batch = (l2 >> 4) * 4 + reg;
            const int n = l2 & 15;
            zbuf[n >> 2][st2 * 4 + (n & 3)][batch] = z;
        }
        __syncthreads();

        if (tid < 32) {
            const int batch = tid >> 2, dp = (tid & 3) << 1;
            float h2[2];
#pragma unroll
            for (int q = 0; q < 2; ++q) {
                const int dl = dp + q;
                const float zi = zbuf[0][dl][batch] + biasL[dl];
                const float zf = zbuf[1][dl][batch] + biasL[8 + dl];
                const float zg = zbuf[2][dl][batch] + biasL[16 + dl];
                const float zo = zbuf[3][dl][batch] + biasL[24 + dl];
                const float si = 1.f / (1.f + expf(-zi));
                const float sf = 1.f / (1.f + expf(-zf));
                const float so = 1.f / (1.f + expf(-zo));
                const float tg = tanhf(zg);
                float& cr = q ? creg1 : creg0;
                cr = sf * cr + si * tg;
                h2[q] = so * tanhf(cr);
            }
            const unsigned int pk = (unsigned int)f2b(h2[0]) |
                                    ((unsigned int)f2b(h2[1]) << 16);
            unsigned int* hp = (unsigned int*)(hout + batch * DD + d0) + (tid & 3);
            __hip_atomic_store(hp, pk, __ATOMIC_RELAXED, __HIP_MEMORY_SCOPE_AGENT);
        }
        if (t != TT - 1) {
            __builtin_amdgcn_s_waitcnt(0);   // h stores at coherence point (L3)
            if (tid == 0)
                __hip_atomic_store(&flags[blockIdx.x * FPAD], (unsigned int)(t + 1),
                                   __ATOMIC_RELAXED, __HIP_MEMORY_SCOPE_AGENT);
        }
    }
}

// ---------------- final linear: out[b,o] = h[b,:]·w_lin[o,:] + b_lin[o] ----------------
__global__ void k_final(const unsigned short* __restrict__ h, const float* __restrict__ w_lin,
                        const float* __restrict__ b_lin, float* __restrict__ out) {
    const int wave = threadIdx.x >> 6;
    const int lane = threadIdx.x & 63;
    const int o = blockIdx.x * 4 + wave;
    const float4* w4 = (const float4*)(w_lin + (size_t)o * DD);

    float acc[8];
#pragma unroll
    for (int b = 0; b < 8; ++b) acc[b] = 0.f;
#pragma unroll 2
    for (int it = 0; it < 8; ++it) {
        const int k4 = it * 64 + lane;
        float4 wv = w4[k4];
#pragma unroll
        for (int b = 0; b < 8; ++b) {
            ushort4 hv = *(const ushort4*)(h + (size_t)b * DD + 4 * (size_t)k4);
            acc[b] += wv.x * b2f(hv.x) + wv.y * b2f(hv.y) +
                      wv.z * b2f(hv.z) + wv.w * b2f(hv.w);
        }
    }
#pragma unroll
    for (int b = 0; b < 8; ++b) {
        float v = acc[b];
        v += __shfl_xor(v, 32, 64);
        v += __shfl_xor(v, 16, 64);
        v += __shfl_xor(v, 8, 64);
        v += __shfl_xor(v, 4, 64);
        v += __shfl_xor(v, 2, 64);
        v += __shfl_xor(v, 1, 64);
        acc[b] = v;
    }
    if (lane < 8) out[(size_t)lane * NN + o] = acc[lane] + b_lin[o];
}

// ---------------- launch ----------------

extern "C" void kernel_launch(void* const* d_in, const int* in_sizes, int n_in,
                              void* d_out, int out_size, void* d_ws, size_t ws_size,
                              hipStream_t stream) {
    const float* xseq  = (const float*)d_in[0];
    const float* gat_w = (const float*)d_in[1];
    const float* a_src = (const float*)d_in[2];
    const float* a_dst = (const float*)d_in[3];
    const float* g_b   = (const float*)d_in[4];
    const float* w_ih  = (const float*)d_in[5];
    const float* w_hh  = (const float*)d_in[6];
    const float* b_ih  = (const float*)d_in[7];
    const float* b_hh  = (const float*)d_in[8];
    const float* w_lin = (const float*)d_in[9];
    const float* b_lin = (const float*)d_in[10];
    const int*   eidx  = (const int*)d_in[11];
    float* out = (float*)d_out;

    // workspace layout
    unsigned short* seq = (unsigned short*)d_ws;                 // T*B*D bf16 (4 MB)
    unsigned short* WP  = seq + (size_t)TT * BB * DD;            // 64 MB packed weights
    unsigned short* hb0 = WP + (size_t)8192 * KTOT;              // B*D bf16
    unsigned short* hb1 = hb0 + BB * DD;                         // B*D bf16
    unsigned int* flags = (unsigned int*)(hb1 + BB * DD);        // 256*FPAD dwords
    int* counts  = (int*)(flags + 256 * FPAD);
    int* offs    = counts + NN;
    int* fill    = offs + NN + 1;
    int* csr_src = fill + NN;

    // CSR build
    k_csr_zero<<<1, NN, 0, stream>>>(counts, fill);
    k_csr_count<<<EE / 256, 256, 0, stream>>>(eidx, counts);
    k_csr_scan<<<1, 1, 0, stream>>>(counts, offs);
    k_csr_fill<<<EE / 256, 256, 0, stream>>>(eidx, offs, fill, csr_src);

    // weight pack (bf16, B-frag swizzled)
    k_pack_w<<<16384, 256, 0, stream>>>(w_ih, w_hh, WP);

    // GAT -> seq (bf16)
    k_gat0<<<TT, NN, 0, stream>>>(xseq, gat_w, a_src, a_dst, g_b, offs, csr_src, seq);
    k_gat_rest<<<(TT * 7 * NN) / 256, 256, 0, stream>>>(xseq, gat_w, g_b, seq);

    // zero h buffers + barrier flags (poisoned with 0xAA each timed call!)
    k_zero<<<64, 256, 0, stream>>>((unsigned int*)hb0, flags);

    // persistent cooperative LSTM with fence-free sc1 barrier
    {
        void* kargs[] = {
            (void*)&seq, (void*)&WP, (void*)&b_ih, (void*)&b_hh,
            (void*)&hb0, (void*)&hb1, (void*)&flags,
        };
        hipLaunchCooperativeKernel((const void*)k_lstm_persist, dim3(256), dim3(1024),
                                   kargs, 0, stream);
    }

    // final h is in hb0 after 128 steps
    k_final<<<NN / 4, 256, 0, stream>>>(hb0, w_lin, b_lin, out);
}